// Round 9
// baseline (174.136 us; speedup 1.0000x reference)
//
#include <hip/hip_runtime.h>
#include <hip/hip_fp16.h>

#define N_NODES 50000
#define N_EDGES 800000
#define D_FEAT  96
#define NBUCK   196                       // ceil(N_NODES / 256)
#define NCHB    256                       // edge-chunk blocks
#define CHUNK   (N_EDGES / NCHB)          // 3125 exactly
#define KMAX    6144                      // max edges per bucket staged in LDS
#define NSLICE  8                         // feature slices == XCD count
#define SDIM    12                        // dims per slice (96/8)
#define NCONV   (N_NODES * NSLICE)        // convert items (row, slice)

typedef float f32x4 __attribute__((ext_vector_type(4)));

// exclusive scan of one value per thread across a 256-thread block
__device__ __forceinline__ int block_excl_scan_256(int v, int tid, int* ws4) {
    int lane = tid & 63, wid = tid >> 6;
    int x = v;
    for (int off = 1; off < 64; off <<= 1) {
        int t = __shfl_up(x, off);
        if (lane >= off) x += t;
    }
    if (lane == 63) ws4[wid] = x;
    __syncthreads();
    int add = 0;
    for (int w = 0; w < wid; ++w) add += ws4[w];
    __syncthreads();
    return x + add - v;
}

__device__ __forceinline__ float2 up2(unsigned u) {
    __half2 h = *reinterpret_cast<__half2*>(&u);
    return __half22float2(h);
}

__device__ __forceinline__ unsigned pk2(float x, float y) {
    __half2 h = __floats2half2_rn(x, y);
    return *reinterpret_cast<unsigned*>(&h);
}

// ---- K1: sliced fp16 table build + coarse LDS histogram (first 256 blocks) --------
// ft8 layout: [slice][node] records of 32 B (12 fp16 dims in 6 dwords + 2 pad)
__global__ __launch_bounds__(256) void convert_hist_kernel(const float* __restrict__ feat,
                                                           unsigned* __restrict__ ft8,
                                                           const int* __restrict__ rows,
                                                           int* __restrict__ blockHist) {
    __shared__ int hist[NBUCK];
    int tid = threadIdx.x, b = blockIdx.x;
    bool doHist = (b < NCHB);
    if (doHist) {
        for (int t = tid; t < NBUCK; t += 256) hist[t] = 0;
        __syncthreads();
    }
    int i = b * 256 + tid;
    if (i < NCONV) {
        int n = i >> 3, s = i & 7;
        const f32x4* src = (const f32x4*)(feat + (size_t)n * D_FEAT + s * SDIM);
        f32x4 fA = __builtin_nontemporal_load(src);
        f32x4 fB = __builtin_nontemporal_load(src + 1);
        f32x4 fC = __builtin_nontemporal_load(src + 2);
        unsigned* dst = ft8 + (size_t)(s * N_NODES + n) * 8;
        uint4 lo = make_uint4(pk2(fA.x, fA.y), pk2(fA.z, fA.w),
                              pk2(fB.x, fB.y), pk2(fB.z, fB.w));
        *(uint4*)dst = lo;
        *(uint2*)(dst + 4) = make_uint2(pk2(fC.x, fC.y), pk2(fC.z, fC.w));
    }
    if (doHist) {
        int sBase = b * CHUNK;
        for (int k = tid; k < CHUNK; k += 256) atomicAdd(&hist[rows[sBase + k] >> 8], 1);
        __syncthreads();
        for (int t = tid; t < NBUCK; t += 256) blockHist[b * NBUCK + t] = hist[t];
    }
}

// ---- K2a: per-bucket exclusive scan over the 256 blocks (one block per bucket) -----
__global__ __launch_bounds__(256) void col_scan_kernel(int* __restrict__ blockHist,
                                                       int* __restrict__ btot) {
    __shared__ int ws4[4];
    int bin = blockIdx.x, j = threadIdx.x;
    int v = blockHist[j * NBUCK + bin];
    int ex = block_excl_scan_256(v, j, ws4);
    blockHist[j * NBUCK + bin] = ex;
    if (j == 255) btot[bin] = ex + v;
}

// ---- K2b: scan 196 bucket totals -> bucket bases ------------------------------------
__global__ __launch_bounds__(256) void bucket_scan_kernel(const int* __restrict__ btot,
                                                          int* __restrict__ bbase,
                                                          int* __restrict__ offsets) {
    __shared__ int ws4[4];
    int t = threadIdx.x;
    int v = (t < NBUCK) ? btot[t] : 0;
    int ex = block_excl_scan_256(v, t, ws4);
    if (t < NBUCK) bbase[t] = ex;
    if (t == 0) { bbase[NBUCK] = N_EDGES; offsets[N_NODES] = N_EDGES; }
}

// ---- K3: scatter edges into coarse buckets (LDS cursors, zero global atomics) ------
__global__ __launch_bounds__(256) void bucket_scatter_kernel(const int* __restrict__ rows,
                                                             const int* __restrict__ cols,
                                                             const float* __restrict__ vals,
                                                             const int* __restrict__ bbase,
                                                             const int* __restrict__ blockHist,
                                                             uint2* __restrict__ bb) {
    __shared__ int cur[NBUCK];
    int b = blockIdx.x, tid = threadIdx.x;
    for (int t = tid; t < NBUCK; t += 256)
        cur[t] = bbase[t] + blockHist[b * NBUCK + t];
    __syncthreads();
    int s = b * CHUNK;
    for (int k = tid; k < CHUNK; k += 256) {
        int e = s + k;
        int r = rows[e];
        unsigned c = (unsigned)cols[e];
        float v = vals[e];
        int pos = atomicAdd(&cur[r >> 8], 1);
        bb[pos] = make_uint2(((unsigned)(r & 255) << 16) | c, __float_as_uint(v));
    }
}

// ---- K4: per-bucket fine sort (in place via LDS stage) + offsets + fused deg/dis ---
__global__ __launch_bounds__(256) void bucket_csr_kernel(const int* __restrict__ bbase,
                                                         uint2* __restrict__ bb,
                                                         int* __restrict__ offsets,
                                                         float* __restrict__ dis) {
    __shared__ uint2 stage[KMAX];
    __shared__ int   hist[256];
    __shared__ float degF[256];
    __shared__ int   ws4[4];
    int bin = blockIdx.x, tid = threadIdx.x;
    int start = bbase[bin], end = bbase[bin + 1];
    int cnt = min(end - start, KMAX);
    hist[tid] = 0;
    degF[tid] = 0.0f;
    __syncthreads();
    for (int k = tid; k < cnt; k += 256) {
        uint2 p = bb[start + k];
        stage[k] = p;
        int rl = p.x >> 16;
        atomicAdd(&hist[rl], 1);
        atomicAdd(&degF[rl], __uint_as_float(p.y));
    }
    __syncthreads();
    int v = hist[tid];
    int ex = block_excl_scan_256(v, tid, ws4);
    int row = bin * 256 + tid;
    if (row < N_NODES) {
        offsets[row] = start + ex;
        float d = degF[tid];
        dis[row] = (d > 0.0f) ? rsqrtf(d) : 0.0f;
    }
    __syncthreads();
    hist[tid] = ex;                 // repurpose as within-bucket cursor
    __syncthreads();
    for (int k = tid; k < cnt; k += 256) {
        uint2 p = stage[k];
        int rl = p.x >> 16;
        int pos = atomicAdd(&hist[rl], 1);
        bb[start + pos] = p;        // safe: all sources staged in LDS
    }
}

// ---- K5: XCD-pinned dimension-sliced pull SpMM -------------------------------------
// slice = blockIdx % 8 -> under round-robin block->XCD mapping, each XCD gathers only
// its own 1.6 MB sub-table (L2-resident). One thread per (row, slice).
__global__ __launch_bounds__(256) void spmm_sliced_kernel(const unsigned* __restrict__ ft8,
                                                          const int* __restrict__ offsets,
                                                          const uint2* __restrict__ pairs,
                                                          const float* __restrict__ dis,
                                                          const int* __restrict__ index,
                                                          float* __restrict__ out) {
    int slice = blockIdx.x & 7;
    int chunk = blockIdx.x >> 3;
    int r = chunk * 256 + threadIdx.x;
    if (r >= N_NODES) return;
    int s = offsets[r], t = offsets[r + 1];
    const unsigned* tab = ft8 + (size_t)slice * N_NODES * 8;
    float a[SDIM] = {0.f, 0.f, 0.f, 0.f, 0.f, 0.f, 0.f, 0.f, 0.f, 0.f, 0.f, 0.f};
    for (int e = s; e < t; ++e) {
        uint2 p = pairs[e];
        unsigned c = p.x & 0xFFFFu;
        float w = __uint_as_float(p.y) * dis[c];
        const unsigned* rec = tab + c * 8u;
        uint4 u4 = *(const uint4*)rec;
        uint2 u2 = *(const uint2*)(rec + 4);
        float2 f;
        f = up2(u4.x); a[0]  += f.x * w; a[1]  += f.y * w;
        f = up2(u4.y); a[2]  += f.x * w; a[3]  += f.y * w;
        f = up2(u4.z); a[4]  += f.x * w; a[5]  += f.y * w;
        f = up2(u4.w); a[6]  += f.x * w; a[7]  += f.y * w;
        f = up2(u2.x); a[8]  += f.x * w; a[9]  += f.y * w;
        f = up2(u2.y); a[10] += f.x * w; a[11] += f.y * w;
    }
    float dr  = dis[r];
    int  orow = index[r];
    f32x4* op = (f32x4*)(out + (size_t)orow * D_FEAT + slice * SDIM);
    f32x4 v0 = {a[0] * dr, a[1] * dr, a[2]  * dr, a[3]  * dr};
    f32x4 v1 = {a[4] * dr, a[5] * dr, a[6]  * dr, a[7]  * dr};
    f32x4 v2 = {a[8] * dr, a[9] * dr, a[10] * dr, a[11] * dr};
    __builtin_nontemporal_store(v0, op);
    __builtin_nontemporal_store(v1, op + 1);
    __builtin_nontemporal_store(v2, op + 2);
}

extern "C" void kernel_launch(void* const* d_in, const int* in_sizes, int n_in,
                              void* d_out, int out_size, void* d_ws, size_t ws_size,
                              hipStream_t stream) {
    const float* features  = (const float*)d_in[0];
    const int*   edge_rows = (const int*)d_in[1];
    const int*   edge_cols = (const int*)d_in[2];
    const float* edge_vals = (const float*)d_in[3];
    const int*   index     = (const int*)d_in[4];
    float* out = (float*)d_out;

    // workspace layout (4-byte units), total ~19.8 MB:
    // [0, 3.2M)            ft8       sliced fp16 table: 8 x 50000 x 32 B
    // [3.2M, 4.8M)         bb        bucketBuf / final CSR pairs (uint2 x E)
    // [4.8M, +50176)       blockHist 256 x 196
    // [4850176, +196)      btot
    // [4850372, +197)      bbase
    // [4850569, +N+1)      offsets
    // [4900570, +N)        dis
    unsigned* wsu     = (unsigned*)d_ws;
    unsigned* ft8     = wsu;
    uint2*    bb      = (uint2*)(wsu + 3200000);
    int*      bhist   = (int*)(wsu + 4800000);
    int*      btot    = (int*)(wsu + 4850176);
    int*      bbase   = (int*)(wsu + 4850372);
    int*      offsets = (int*)(wsu + 4850569);
    float*    dis     = (float*)(wsu + 4900570);

    int cblk = (NCONV + 255) / 256;       // 1563 blocks; first 256 also do hist
    convert_hist_kernel<<<cblk, 256, 0, stream>>>(features, ft8, edge_rows, bhist);
    col_scan_kernel<<<NBUCK, 256, 0, stream>>>(bhist, btot);
    bucket_scan_kernel<<<1, 256, 0, stream>>>(btot, bbase, offsets);
    bucket_scatter_kernel<<<NCHB, 256, 0, stream>>>(edge_rows, edge_cols, edge_vals,
                                                    bbase, bhist, bb);
    bucket_csr_kernel<<<NBUCK, 256, 0, stream>>>(bbase, bb, offsets, dis);

    spmm_sliced_kernel<<<NSLICE * NBUCK, 256, 0, stream>>>(ft8, offsets, bb,
                                                           dis, index, out);
}

// Round 10
// 70.336 us; speedup vs baseline: 2.4758x; 2.4758x over previous
//
#include <hip/hip_runtime.h>
#include <hip/hip_fp16.h>

#define N_NODES 50000
#define N_EDGES 800000
#define D_FEAT  96
#define NBUCK   196                       // ceil(N_NODES / 256)
#define NCHB    256                       // edge-chunk blocks
#define CHUNK   (N_EDGES / NCHB)          // 3125 exactly
#define KMAX    6144                      // max edges per bucket staged in LDS (mean 4096)
#define N4      (N_NODES * D_FEAT / 4)    // 1,200,000 float4s

// exclusive scan of one value per thread across a 256-thread block
__device__ __forceinline__ int block_excl_scan_256(int v, int tid, int* ws4) {
    int lane = tid & 63, wid = tid >> 6;
    int x = v;
    for (int off = 1; off < 64; off <<= 1) {
        int t = __shfl_up(x, off);
        if (lane >= off) x += t;
    }
    if (lane == 63) ws4[wid] = x;
    __syncthreads();
    int add = 0;
    for (int w = 0; w < wid; ++w) add += ws4[w];
    __syncthreads();
    return x + add - v;
}

__device__ __forceinline__ float2 up2(unsigned u) {
    __half2 h = *reinterpret_cast<__half2*>(&u);
    return __half22float2(h);
}

// ---- K1: fp16 table build (grid-stride) + coarse LDS histogram for first 256 blocks
__global__ __launch_bounds__(256) void convert_hist_kernel(const float4* __restrict__ feat,
                                                           uint2* __restrict__ ft,
                                                           const int* __restrict__ rows,
                                                           int* __restrict__ blockHist) {
    __shared__ int hist[NBUCK];
    int tid = threadIdx.x, b = blockIdx.x;
    for (int i = b * 256 + tid; i < N4; i += 1024 * 256) {
        float4 f = feat[i];
        __half2 h01 = __floats2half2_rn(f.x, f.y);
        __half2 h23 = __floats2half2_rn(f.z, f.w);
        ft[i] = make_uint2(*(unsigned*)&h01, *(unsigned*)&h23);
    }
    if (b < NCHB) {
        for (int t = tid; t < NBUCK; t += 256) hist[t] = 0;
        __syncthreads();
        int s = b * CHUNK;
        for (int k = tid; k < CHUNK; k += 256) atomicAdd(&hist[rows[s + k] >> 8], 1);
        __syncthreads();
        for (int t = tid; t < NBUCK; t += 256) blockHist[b * NBUCK + t] = hist[t];
    }
}

// ---- K2a: per-bucket exclusive scan over the 256 blocks (one block per bucket) -----
__global__ __launch_bounds__(256) void col_scan_kernel(int* __restrict__ blockHist,
                                                       int* __restrict__ btot) {
    __shared__ int ws4[4];
    int bin = blockIdx.x, j = threadIdx.x;
    int v = blockHist[j * NBUCK + bin];
    int ex = block_excl_scan_256(v, j, ws4);
    blockHist[j * NBUCK + bin] = ex;
    if (j == 255) btot[bin] = ex + v;
}

// ---- K2b: scan 196 bucket totals -> bucket bases ------------------------------------
__global__ __launch_bounds__(256) void bucket_scan_kernel(const int* __restrict__ btot,
                                                          int* __restrict__ bbase,
                                                          int* __restrict__ offsets) {
    __shared__ int ws4[4];
    int t = threadIdx.x;
    int v = (t < NBUCK) ? btot[t] : 0;
    int ex = block_excl_scan_256(v, t, ws4);
    if (t < NBUCK) bbase[t] = ex;
    if (t == 0) { bbase[NBUCK] = N_EDGES; offsets[N_NODES] = N_EDGES; }
}

// ---- K3: scatter edges into coarse buckets (LDS cursors, zero global atomics) ------
__global__ __launch_bounds__(256) void bucket_scatter_kernel(const int* __restrict__ rows,
                                                             const int* __restrict__ cols,
                                                             const float* __restrict__ vals,
                                                             const int* __restrict__ bbase,
                                                             const int* __restrict__ blockHist,
                                                             uint2* __restrict__ bb) {
    __shared__ int cur[NBUCK];
    int b = blockIdx.x, tid = threadIdx.x;
    for (int t = tid; t < NBUCK; t += 256)
        cur[t] = bbase[t] + blockHist[b * NBUCK + t];
    __syncthreads();
    int s = b * CHUNK;
    for (int k = tid; k < CHUNK; k += 256) {
        int e = s + k;
        int r = rows[e];
        unsigned c = (unsigned)cols[e];
        float v = vals[e];
        int pos = atomicAdd(&cur[r >> 8], 1);
        bb[pos] = make_uint2(((unsigned)(r & 255) << 16) | c, __float_as_uint(v));
    }
}

// ---- K4: per-bucket fine sort (in place via LDS stage) + offsets + fused deg/dis ---
__global__ __launch_bounds__(256) void bucket_csr_kernel(const int* __restrict__ bbase,
                                                         uint2* __restrict__ bb,
                                                         int* __restrict__ offsets,
                                                         float* __restrict__ dis) {
    __shared__ uint2 stage[KMAX];
    __shared__ int   hist[256];
    __shared__ float degF[256];
    __shared__ int   ws4[4];
    int bin = blockIdx.x, tid = threadIdx.x;
    int start = bbase[bin], end = bbase[bin + 1];
    int cnt = min(end - start, KMAX);
    hist[tid] = 0;
    degF[tid] = 0.0f;
    __syncthreads();
    for (int k = tid; k < cnt; k += 256) {
        uint2 p = bb[start + k];
        stage[k] = p;
        int rl = p.x >> 16;
        atomicAdd(&hist[rl], 1);
        atomicAdd(&degF[rl], __uint_as_float(p.y));
    }
    __syncthreads();
    int v = hist[tid];
    int ex = block_excl_scan_256(v, tid, ws4);
    int row = bin * 256 + tid;
    if (row < N_NODES) {
        offsets[row] = start + ex;
        float d = degF[tid];
        dis[row] = (d > 0.0f) ? rsqrtf(d) : 0.0f;
    }
    __syncthreads();
    hist[tid] = ex;                 // repurpose as within-bucket cursor
    __syncthreads();
    for (int k = tid; k < cnt; k += 256) {
        uint2 p = stage[k];
        int rl = p.x >> 16;
        int pos = atomicAdd(&hist[rl], 1);
        bb[start + pos] = p;        // safe: all sources staged in LDS
    }
}

// ---- K5: pull SpMM over fp16 table, 12 thr/row x uint4 loads, unroll 2 -------------
__global__ __launch_bounds__(256) void spmm_kernel(const uint4* __restrict__ ftab,
                                                   const int* __restrict__ offsets,
                                                   const uint2* __restrict__ pairs,
                                                   const float* __restrict__ dis,
                                                   const int* __restrict__ index,
                                                   float* __restrict__ out) {
    int gid  = blockIdx.x * 256 + threadIdx.x;
    int r    = gid / 12;
    int lane = gid % 12;
    if (r >= N_NODES) return;
    int s = offsets[r], t = offsets[r + 1];
    float a0 = 0.f, a1 = 0.f, a2 = 0.f, a3 = 0.f, a4 = 0.f, a5 = 0.f, a6 = 0.f, a7 = 0.f;
    int e = s;
    for (; e + 1 < t; e += 2) {
        uint2 pa = pairs[e], pb = pairs[e + 1];
        unsigned ca = pa.x & 0xFFFFu, cb = pb.x & 0xFFFFu;
        float wa = __uint_as_float(pa.y) * dis[ca];
        float wb = __uint_as_float(pb.y) * dis[cb];
        uint4 ua = ftab[ca * 12u + lane];
        uint4 ub = ftab[cb * 12u + lane];
        float2 f;
        f = up2(ua.x); a0 += f.x * wa; a1 += f.y * wa;
        f = up2(ua.y); a2 += f.x * wa; a3 += f.y * wa;
        f = up2(ua.z); a4 += f.x * wa; a5 += f.y * wa;
        f = up2(ua.w); a6 += f.x * wa; a7 += f.y * wa;
        f = up2(ub.x); a0 += f.x * wb; a1 += f.y * wb;
        f = up2(ub.y); a2 += f.x * wb; a3 += f.y * wb;
        f = up2(ub.z); a4 += f.x * wb; a5 += f.y * wb;
        f = up2(ub.w); a6 += f.x * wb; a7 += f.y * wb;
    }
    if (e < t) {
        uint2 pa = pairs[e];
        unsigned ca = pa.x & 0xFFFFu;
        float wa = __uint_as_float(pa.y) * dis[ca];
        uint4 ua = ftab[ca * 12u + lane];
        float2 f;
        f = up2(ua.x); a0 += f.x * wa; a1 += f.y * wa;
        f = up2(ua.y); a2 += f.x * wa; a3 += f.y * wa;
        f = up2(ua.z); a4 += f.x * wa; a5 += f.y * wa;
        f = up2(ua.w); a6 += f.x * wa; a7 += f.y * wa;
    }
    float dr  = dis[r];
    int  orow = index[r];
    float4* op = (float4*)(out + (size_t)orow * D_FEAT) + lane * 2;
    op[0] = make_float4(a0 * dr, a1 * dr, a2 * dr, a3 * dr);
    op[1] = make_float4(a4 * dr, a5 * dr, a6 * dr, a7 * dr);
}

extern "C" void kernel_launch(void* const* d_in, const int* in_sizes, int n_in,
                              void* d_out, int out_size, void* d_ws, size_t ws_size,
                              hipStream_t stream) {
    const float* features  = (const float*)d_in[0];
    const int*   edge_rows = (const int*)d_in[1];
    const int*   edge_cols = (const int*)d_in[2];
    const float* edge_vals = (const float*)d_in[3];
    const int*   index     = (const int*)d_in[4];
    float* out = (float*)d_out;

    // workspace layout (4-byte units), total ~16.6 MB:
    // [0, 2.4M)            ft        fp16 feature table (N*48 uints, 16B aligned)
    // [2.4M, 4.0M)         bb        bucketBuf / final CSR pairs (uint2 x E)
    // [4.0M, +50176)       blockHist 256 x 196
    // [4050176, +196)      btot
    // [4050372, +197)      bbase
    // [4050569, +N+1)      offsets
    // [4100570, +N)        dis
    unsigned* wsu     = (unsigned*)d_ws;
    uint2*    ft      = (uint2*)wsu;
    uint2*    bb      = (uint2*)(wsu + 2400000);
    int*      bhist   = (int*)(wsu + 4000000);
    int*      btot    = (int*)(wsu + 4050176);
    int*      bbase   = (int*)(wsu + 4050372);
    int*      offsets = (int*)(wsu + 4050569);
    float*    dis     = (float*)(wsu + 4100570);

    convert_hist_kernel<<<1024, 256, 0, stream>>>((const float4*)features, ft,
                                                  edge_rows, bhist);
    col_scan_kernel<<<NBUCK, 256, 0, stream>>>(bhist, btot);
    bucket_scan_kernel<<<1, 256, 0, stream>>>(btot, bbase, offsets);
    bucket_scatter_kernel<<<NCHB, 256, 0, stream>>>(edge_rows, edge_cols, edge_vals,
                                                    bbase, bhist, bb);
    bucket_csr_kernel<<<NBUCK, 256, 0, stream>>>(bbase, bb, offsets, dis);

    int total = N_NODES * 12;
    spmm_kernel<<<(total + 255) / 256, 256, 0, stream>>>((const uint4*)ft, offsets, bb,
                                                         dis, index, out);
}